// Round 3
// baseline (560.367 us; speedup 1.0000x reference)
//
#include <hip/hip_runtime.h>
#include <math.h>

#define T 64
#define NN 16384
#define NE 262144
#define FIN 8
#define H1H 12
#define C1C 16
#define HID 192
#define CAP2 95      // max recorded in-edges of node 0 per t (Poisson(16); P(>=95) ~ 0)
#define SCAP 96      // max active nodes per t (CAP2 sources + node 0)
#define DEGCAP 127   // max recorded in-degree of an active node (Poisson(16))
#define LH 128
#define G4 512
#define NB 32
#define NL 32

#define DEV __device__ __forceinline__

DEV float wave_max(float v){
  #pragma unroll
  for (int m = 32; m; m >>= 1) v = fmaxf(v, __shfl_xor(v, m));
  return v;
}
DEV float wave_sum(float v){
  #pragma unroll
  for (int m = 32; m; m >>= 1) v += __shfl_xor(v, m);
  return v;
}
DEV float leaky(float x){ return x >= 0.f ? x : 0.2f * x; }
DEV float sigmoidf(float x){ return 1.f / (1.f + expf(-x)); }

// alpha = 0.8*a + 0.1*s + 0.1*v with s: rows {1,2,12,19,22}->0, {7,14}->1
//                                  v: rows {10,13}->0.5, {17}->0
// => rows {1,2,7,10,12,13,14,17,19,22}: 0.9a; {7,14}: +0.1; {10,13}: +0.05
DEV float apply_edit(float a, int eid){
  if (eid >= 32) return a;
  const unsigned m09 = (1u<<1)|(1u<<2)|(1u<<7)|(1u<<10)|(1u<<12)|(1u<<13)|(1u<<14)|(1u<<17)|(1u<<19)|(1u<<22);
  const unsigned mp1 = (1u<<7)|(1u<<14);
  const unsigned mp05 = (1u<<10)|(1u<<13);
  unsigned b = 1u << eid;
  float r = (m09 & b) ? 0.9f * a : a;
  if (mp1 & b) r += 0.1f;
  if (mp05 & b) r += 0.05f;
  return r;
}

// ---- K1: find edges with dst==0 per timestep ----
__global__ __launch_bounds__(256) void k_scan0(const int* __restrict__ ei,
                                               int* __restrict__ cnt2, int* __restrict__ list2){
  long long gid = (long long)blockIdx.x * blockDim.x + threadIdx.x;
  long long e4 = gid * 4;
  int t = (int)(e4 >> 18);
  int e = (int)(e4 & (NE - 1));
  const int* dstp = ei + (size_t)t * 2 * NE + NE + e;
  int4 d = *(const int4*)dstp;
  int dd[4] = {d.x, d.y, d.z, d.w};
  #pragma unroll
  for (int q = 0; q < 4; q++){
    if (dd[q] == 0){
      int pos = atomicAdd(&cnt2[t], 1);
      if (pos < CAP2) list2[t * CAP2 + pos] = e + q;
    }
  }
}

// ---- K2: build active node set S = {sources of dst-0 edges} ∪ {0}, with slot map ----
__global__ __launch_bounds__(128) void k_build(const int* __restrict__ ei, const int* __restrict__ cnt2,
                                               const int* __restrict__ list2, int* __restrict__ scnt,
                                               int* __restrict__ Slist, int* __restrict__ slot_of){
  int t = blockIdx.x;
  int* so = slot_of + (size_t)t * NN;
  int m = min(cnt2[t], CAP2);
  for (int i = threadIdx.x; i < m + 1; i += blockDim.x){
    int u = (i == m) ? 0 : ei[(size_t)t * 2 * NE + list2[t * CAP2 + i]];
    int old = atomicCAS(&so[u], -1, -2);
    if (old == -1){
      int s = atomicAdd(&scnt[t], 1);
      Slist[t * SCAP + s] = u;
      __hip_atomic_store(&so[u], s, __ATOMIC_RELEASE, __HIP_MEMORY_SCOPE_AGENT);
    }
  }
}

// ---- K3: collect in-edges of every node in S ----
__global__ __launch_bounds__(256) void k_scan1(const int* __restrict__ ei, const int* __restrict__ slot_of,
                                               int* __restrict__ ecnt1, int* __restrict__ elist1){
  long long gid = (long long)blockIdx.x * blockDim.x + threadIdx.x;
  long long e4 = gid * 4;
  int t = (int)(e4 >> 18);
  int e = (int)(e4 & (NE - 1));
  const int* dstp = ei + (size_t)t * 2 * NE + NE + e;
  int4 d = *(const int4*)dstp;
  int dd[4] = {d.x, d.y, d.z, d.w};
  #pragma unroll
  for (int q = 0; q < 4; q++){
    int sl = slot_of[(size_t)t * NN + dd[q]];
    if (sl >= 0){
      int pos = atomicAdd(&ecnt1[t * SCAP + sl], 1);
      if (pos < DEGCAP) elist1[((size_t)t * SCAP + sl) * DEGCAP + pos] = e + q;
    }
  }
}

// ---- K4: layer-1 GAT at active nodes. One wave per (t, slot). ----
__global__ __launch_bounds__(64) void k_gat1(const float* __restrict__ x, const int* __restrict__ ei,
                                             const float* __restrict__ Wl1, const float* __restrict__ attl,
                                             const float* __restrict__ attr, const float* __restrict__ b1,
                                             const int* __restrict__ scnt, const int* __restrict__ Slist,
                                             const int* __restrict__ ecnt1, const int* __restrict__ elist1,
                                             float* __restrict__ h1){
  int t = blockIdx.y, s = blockIdx.x;
  if (s >= scnt[t]) return;
  int lane = threadIdx.x;
  int u = Slist[t * SCAP + s];
  int deg = min(ecnt1[t * SCAP + s], DEGCAP);
  int tot = deg + 1;                      // + self loop (appended after edges; id >= NE, never special)
  bool two = tot > 64;                    // wave-uniform: second chunk needed (rare: deg ~ Poisson(16))
  const float* xt = x + (size_t)t * NN * FIN;
  const int* srcp = ei + (size_t)t * 2 * NE;
  const int* el = elist1 + ((size_t)t * SCAP + s) * DEGCAP;

  float xu[FIN];
  #pragma unroll
  for (int f = 0; f < FIN; f++) xu[f] = xt[(size_t)u * FIN + f];

  // chunk 0 (lanes 0..63)
  bool act0 = lane < tot;
  int eid0 = 1 << 29;
  int su0 = u;
  if (lane < deg){ int e = el[lane]; eid0 = e; su0 = srcp[e]; }
  float xsrc0[FIN];
  #pragma unroll
  for (int f = 0; f < FIN; f++) xsrc0[f] = xt[(size_t)su0 * FIN + f];

  // chunk 1 (lanes 64..127) — only if deg+1 > 64
  bool act1 = false; int eid1 = 1 << 29;
  float xsrc1[FIN];
  if (two){
    int idx = 64 + lane;
    act1 = idx < tot;
    int su1 = u;
    if (idx < deg){ int e = el[idx]; eid1 = e; su1 = srcp[e]; }
    #pragma unroll
    for (int f = 0; f < FIN; f++) xsrc1[f] = xt[(size_t)su1 * FIN + f];
  }

  float* h1p = h1 + ((size_t)t * SCAP + s) * HID;
  for (int h = 0; h < H1H; h++){
    // xl of dst node -> ar
    float xlu[C1C];
    #pragma unroll
    for (int c = 0; c < C1C; c++){
      float v = 0.f;
      #pragma unroll
      for (int f = 0; f < FIN; f++) v += xu[f] * Wl1[f * HID + h * C1C + c];
      xlu[c] = v;
    }
    float ar = 0.f;
    #pragma unroll
    for (int c = 0; c < C1C; c++) ar += xlu[c] * attr[h * C1C + c];

    float xls0[C1C], xls1[C1C];
    float raw0, raw1 = -INFINITY;
    {
      float al = 0.f;
      #pragma unroll
      for (int c = 0; c < C1C; c++){
        float v = 0.f;
        #pragma unroll
        for (int f = 0; f < FIN; f++) v += xsrc0[f] * Wl1[f * HID + h * C1C + c];
        xls0[c] = v;
        al += v * attl[h * C1C + c];
      }
      raw0 = act0 ? leaky(al + ar) : -INFINITY;
    }
    if (two){
      float al = 0.f;
      #pragma unroll
      for (int c = 0; c < C1C; c++){
        float v = 0.f;
        #pragma unroll
        for (int f = 0; f < FIN; f++) v += xsrc1[f] * Wl1[f * HID + h * C1C + c];
        xls1[c] = v;
        al += v * attl[h * C1C + c];
      }
      raw1 = act1 ? leaky(al + ar) : -INFINITY;
    }
    float M = wave_max(fmaxf(raw0, raw1));
    float ex0 = act0 ? expf(raw0 - M) : 0.f;
    float ex1 = act1 ? expf(raw1 - M) : 0.f;
    float S = wave_sum(ex0 + ex1);
    float den = S + 1e-16f;
    float alpha0 = apply_edit(ex0 / den, eid0);
    float alpha1 = two ? apply_edit(ex1 / den, eid1) : 0.f;

    #pragma unroll
    for (int c = 0; c < C1C; c++){
      float contrib = xls0[c] * alpha0;
      if (two) contrib += xls1[c] * alpha1;
      contrib = wave_sum(contrib);
      if (lane == 0){
        float v = contrib + b1[h * C1C + c];
        h1p[h * C1C + c] = v > 0.f ? v : expm1f(v);   // ELU
      }
    }
  }
}

// ---- K5: layer-2 GAT at node 0 only -> series[t]. One wave per t. ----
__global__ __launch_bounds__(64) void k_gat2(const int* __restrict__ ei, const float* __restrict__ Wl2,
                                             const float* __restrict__ attl2_, const float* __restrict__ attr2_,
                                             const float* __restrict__ b2, const int* __restrict__ cnt2,
                                             const int* __restrict__ list2, const int* __restrict__ slot_of,
                                             const float* __restrict__ h1, float* __restrict__ series){
  int t = blockIdx.x; int lane = threadIdx.x;
  int deg = min(cnt2[t], CAP2);
  int tot = deg + 1;
  const int* srcp = ei + (size_t)t * 2 * NE;
  const int* so = slot_of + (size_t)t * NN;
  float attl2 = attl2_[0], attr2 = attr2_[0];
  int sl0 = so[0];
  const float* h1t = h1 + (size_t)t * SCAP * HID;

  float x0 = 0.f;
  for (int k = 0; k < HID; k++) x0 += h1t[(size_t)sl0 * HID + k] * Wl2[k];

  bool act[2]; int eid[2]; float xl2[2];
  #pragma unroll
  for (int ch = 0; ch < 2; ch++){
    int idx = ch * 64 + lane;
    act[ch] = idx < tot;
    eid[ch] = 1 << 29;
    int sl = sl0;
    if (idx < deg){ int e = list2[t * CAP2 + idx]; eid[ch] = e; sl = so[srcp[e]]; }
    float v = 0.f;
    if (act[ch]) for (int k = 0; k < HID; k++) v += h1t[(size_t)sl * HID + k] * Wl2[k];
    xl2[ch] = v;
  }
  float raw[2];
  #pragma unroll
  for (int ch = 0; ch < 2; ch++) raw[ch] = act[ch] ? leaky(attl2 * xl2[ch] + attr2 * x0) : -INFINITY;
  float M = wave_max(fmaxf(raw[0], raw[1]));
  float ex[2];
  #pragma unroll
  for (int ch = 0; ch < 2; ch++) ex[ch] = act[ch] ? expf(raw[ch] - M) : 0.f;
  float S = wave_sum(ex[0] + ex[1]);
  float den = S + 1e-16f;
  float contrib = apply_edit(ex[0] / den, eid[0]) * xl2[0] + apply_edit(ex[1] / den, eid[1]) * xl2[1];
  contrib = wave_sum(contrib);
  if (lane == 0) series[t] = contrib + b2[0];   // 1 head, mean == identity
}

// ---- K7: LSTM, 3-station pipeline. blocks 0-31: layer0 (Whh0), 32-63: Wih1 matmul, 64-95: layer1 (Whh1). ----
// Round-1: VGPR=100 (spill). Round-2: launch_bounds(512,2) alone gave VGPR=116 — the compiler
// REMATERIALIZES the const weight loads every step instead of keeping them resident (legal for
// const __restrict__ data). Fix: asm volatile "+v" pin after the load — a volatile asm result
// cannot be re-derived, forcing true register residency (~128 wgt + ~50 work < 256 cap @ 2 w/EU).
#define AT_LOAD(p)    __hip_atomic_load((p), __ATOMIC_RELAXED, __HIP_MEMORY_SCOPE_AGENT)
#define AT_STORE(p,v) __hip_atomic_store((p), (v), __ATOMIC_RELAXED, __HIP_MEMORY_SCOPE_AGENT)

DEV void pin128(float4* w4){
  #pragma unroll
  for (int m = 0; m < 32; m++){
    asm volatile("" : "+v"(w4[m].x), "+v"(w4[m].y), "+v"(w4[m].z), "+v"(w4[m].w));
  }
}

DEV float dot128(const float4* __restrict__ w4, const float4* __restrict__ h4){
  float a0 = 0.f, a1 = 0.f, a2 = 0.f, a3 = 0.f;
  #pragma unroll
  for (int m = 0; m < 32; m++){
    float4 hv = h4[m];
    a0 = fmaf(w4[m].x, hv.x, a0);
    a1 = fmaf(w4[m].y, hv.y, a1);
    a2 = fmaf(w4[m].z, hv.z, a2);
    a3 = fmaf(w4[m].w, hv.w, a3);
  }
  return (a0 + a1) + (a2 + a3);
}

__global__ __launch_bounds__(512, 2) void k_lstm(const float* __restrict__ series,
    const float* __restrict__ Wih0, const float* __restrict__ Whh0,
    const float* __restrict__ bih0, const float* __restrict__ bhh0,
    const float* __restrict__ Wih1, const float* __restrict__ Whh1,
    const float* __restrict__ bih1, const float* __restrict__ bhh1,
    const float* __restrict__ Wlin, const float* __restrict__ blin,
    float* __restrict__ h0g, float* __restrict__ xpart,
    int* __restrict__ flagA, int* __restrict__ flagB, float* __restrict__ out){
  int j = threadIdx.x;
  int st = blockIdx.x >> 5;
  int b = blockIdx.x & 31;     // stations of batch b land on blocks b, b+32, b+64 -> same XCD (32%8==0)
  __shared__ __align__(16) float h_lds[LH];
  __shared__ __align__(16) float c_lds[LH];
  __shared__ float gate_lds[G4];
  __shared__ float s_series[NL];
  const float4* h4 = (const float4*)h_lds;

  if (st == 0){
    float4 w4[32];
    const float4* Wr = (const float4*)(Whh0 + (size_t)j * LH);
    #pragma unroll
    for (int m = 0; m < 32; m++) w4[m] = Wr[m];
    pin128(w4);
    float wih = Wih0[j];
    float bsum = bih0[j] + bhh0[j];
    if (j < LH){ h_lds[j] = 0.f; c_lds[j] = 0.f; }
    if (j < NL) s_series[j] = series[b + j];
    __syncthreads();
    for (int t = 0; t < NL; t++){
      float acc = fmaf(wih, s_series[t], bsum) + dot128(w4, h4);
      gate_lds[j] = acc;
      __syncthreads();
      if (j < LH){
        float ig = sigmoidf(gate_lds[j]);
        float fg = sigmoidf(gate_lds[LH + j]);
        float gg = tanhf(gate_lds[2 * LH + j]);
        float og = sigmoidf(gate_lds[3 * LH + j]);
        float c = fg * c_lds[j] + ig * gg;
        float h = og * tanhf(c);
        c_lds[j] = c; h_lds[j] = h;
        AT_STORE(&h0g[(b * NL + t) * LH + j], h);
      }
      __syncthreads();   // all stores drained + h_lds ready for next step
      if (j == 0){
        __threadfence();
        __hip_atomic_store(&flagA[b], t + 1, __ATOMIC_RELEASE, __HIP_MEMORY_SCOPE_AGENT);
      }
    }
  } else if (st == 1){
    float4 w4[32];
    const float4* Wr = (const float4*)(Wih1 + (size_t)j * LH);
    #pragma unroll
    for (int m = 0; m < 32; m++) w4[m] = Wr[m];
    pin128(w4);
    for (int t = 0; t < NL; t++){
      if (j == 0){
        while (__hip_atomic_load(&flagA[b], __ATOMIC_ACQUIRE, __HIP_MEMORY_SCOPE_AGENT) < t + 1)
          __builtin_amdgcn_s_sleep(2);
      }
      __syncthreads();
      if (j < LH) h_lds[j] = AT_LOAD(&h0g[(b * NL + t) * LH + j]);
      __syncthreads();
      AT_STORE(&xpart[(b * NL + t) * G4 + j], dot128(w4, h4));
      __syncthreads();
      if (j == 0){
        __threadfence();
        __hip_atomic_store(&flagB[b], t + 1, __ATOMIC_RELEASE, __HIP_MEMORY_SCOPE_AGENT);
      }
    }
  } else {
    float4 w4[32];
    const float4* Wr = (const float4*)(Whh1 + (size_t)j * LH);
    #pragma unroll
    for (int m = 0; m < 32; m++) w4[m] = Wr[m];
    pin128(w4);
    float bsum = bih1[j] + bhh1[j];
    if (j < LH){ h_lds[j] = 0.f; c_lds[j] = 0.f; }
    __syncthreads();
    for (int t = 0; t < NL; t++){
      if (j == 0){
        while (__hip_atomic_load(&flagB[b], __ATOMIC_ACQUIRE, __HIP_MEMORY_SCOPE_AGENT) < t + 1)
          __builtin_amdgcn_s_sleep(2);
      }
      __syncthreads();
      float acc = AT_LOAD(&xpart[(b * NL + t) * G4 + j]) + bsum + dot128(w4, h4);
      gate_lds[j] = acc;
      __syncthreads();
      if (j < LH){
        float ig = sigmoidf(gate_lds[j]);
        float fg = sigmoidf(gate_lds[LH + j]);
        float gg = tanhf(gate_lds[2 * LH + j]);
        float og = sigmoidf(gate_lds[3 * LH + j]);
        float c = fg * c_lds[j] + ig * gg;
        float h = og * tanhf(c);
        c_lds[j] = c; h_lds[j] = h;
      }
      __syncthreads();
    }
    if (j == 0){
      float s2 = blin[0];
      for (int k = 0; k < LH; k++) s2 += Wlin[k] * h_lds[k];
      out[b] = s2;
    }
  }
}

extern "C" void kernel_launch(void* const* d_in, const int* in_sizes, int n_in,
                              void* d_out, int out_size, void* d_ws, size_t ws_size,
                              hipStream_t stream) {
  const float* x     = (const float*)d_in[0];
  const int*   ei    = (const int*)  d_in[1];
  const float* Wl1   = (const float*)d_in[2];
  const float* attl1 = (const float*)d_in[3];
  const float* attr1 = (const float*)d_in[4];
  const float* b1    = (const float*)d_in[5];
  const float* Wl2   = (const float*)d_in[6];
  const float* attl2 = (const float*)d_in[7];
  const float* attr2 = (const float*)d_in[8];
  const float* b2    = (const float*)d_in[9];
  const float* Wih0  = (const float*)d_in[10];
  const float* Whh0  = (const float*)d_in[11];
  const float* bih0  = (const float*)d_in[12];
  const float* bhh0  = (const float*)d_in[13];
  const float* Wih1  = (const float*)d_in[14];
  const float* Whh1  = (const float*)d_in[15];
  const float* bih1  = (const float*)d_in[16];
  const float* bhh1  = (const float*)d_in[17];
  const float* Wlin  = (const float*)d_in[18];
  const float* blin  = (const float*)d_in[19];
  float* out = (float*)d_out;

  char* wsb = (char*)d_ws;
  size_t off = 0;
  auto alloc = [&](size_t bytes)->void*{
    void* p = wsb + off;
    off += (bytes + 255) & ~(size_t)255;
    return p;
  };
  // control region (must be zeroed each launch — ws is poisoned 0xAA)
  int* cnt2  = (int*)alloc(T * 4);
  int* scnt  = (int*)alloc(T * 4);
  int* ecnt1 = (int*)alloc(T * SCAP * 4);
  int* flagA = (int*)alloc(NB * 4);
  int* flagB = (int*)alloc(NB * 4);
  size_t ctrl_bytes = off;
  int* slot_of = (int*)alloc((size_t)T * NN * 4);       // memset 0xFF -> -1
  int* list2   = (int*)alloc((size_t)T * CAP2 * 4);
  int* Slist   = (int*)alloc((size_t)T * SCAP * 4);
  int* elist1  = (int*)alloc((size_t)T * SCAP * DEGCAP * 4);
  float* h1    = (float*)alloc((size_t)T * SCAP * HID * 4);
  float* series= (float*)alloc(T * 4);
  float* h0g   = (float*)alloc((size_t)NB * NL * LH * 4);
  float* xpart = (float*)alloc((size_t)NB * NL * G4 * 4);

  hipMemsetAsync(d_ws, 0, ctrl_bytes, stream);
  hipMemsetAsync(slot_of, 0xFF, (size_t)T * NN * 4, stream);

  k_scan0<<<T * NE / 4 / 256, 256, 0, stream>>>(ei, cnt2, list2);
  k_build<<<T, 128, 0, stream>>>(ei, cnt2, list2, scnt, Slist, slot_of);
  k_scan1<<<T * NE / 4 / 256, 256, 0, stream>>>(ei, slot_of, ecnt1, elist1);
  k_gat1<<<dim3(SCAP, T), 64, 0, stream>>>(x, ei, Wl1, attl1, attr1, b1, scnt, Slist, ecnt1, elist1, h1);
  k_gat2<<<T, 64, 0, stream>>>(ei, Wl2, attl2, attr2, b2, cnt2, list2, slot_of, h1, series);
  k_lstm<<<96, 512, 0, stream>>>(series, Wih0, Whh0, bih0, bhh0, Wih1, Whh1, bih1, bhh1,
                                 Wlin, blin, h0g, xpart, flagA, flagB, out);
}

// Round 4
// 478.333 us; speedup vs baseline: 1.1715x; 1.1715x over previous
//
#include <hip/hip_runtime.h>
#include <math.h>

#define T 64
#define NN 16384
#define NE 262144
#define FIN 8
#define H1H 12
#define C1C 16
#define HID 192
#define CAP2 95      // max recorded in-edges of node 0 per t (Poisson(16); P(>=95) ~ 0)
#define SCAP 96      // max active nodes per t (CAP2 sources + node 0)
#define DEGCAP 127   // max recorded in-degree of an active node (Poisson(16))
#define LH 128
#define G4 512
#define NB 32
#define NL 32

#define DEV __device__ __forceinline__

DEV float wave_max(float v){
  #pragma unroll
  for (int m = 32; m; m >>= 1) v = fmaxf(v, __shfl_xor(v, m));
  return v;
}
DEV float wave_sum(float v){
  #pragma unroll
  for (int m = 32; m; m >>= 1) v += __shfl_xor(v, m);
  return v;
}
DEV float leaky(float x){ return x >= 0.f ? x : 0.2f * x; }
DEV float sigmoidf(float x){ return 1.f / (1.f + expf(-x)); }

// alpha = 0.8*a + 0.1*s + 0.1*v with s: rows {1,2,12,19,22}->0, {7,14}->1
//                                  v: rows {10,13}->0.5, {17}->0
// => rows {1,2,7,10,12,13,14,17,19,22}: 0.9a; {7,14}: +0.1; {10,13}: +0.05
DEV float apply_edit(float a, int eid){
  if (eid >= 32) return a;
  const unsigned m09 = (1u<<1)|(1u<<2)|(1u<<7)|(1u<<10)|(1u<<12)|(1u<<13)|(1u<<14)|(1u<<17)|(1u<<19)|(1u<<22);
  const unsigned mp1 = (1u<<7)|(1u<<14);
  const unsigned mp05 = (1u<<10)|(1u<<13);
  unsigned b = 1u << eid;
  float r = (m09 & b) ? 0.9f * a : a;
  if (mp1 & b) r += 0.1f;
  if (mp05 & b) r += 0.05f;
  return r;
}

// ---- K1: find edges with dst==0 per timestep ----
__global__ __launch_bounds__(256) void k_scan0(const int* __restrict__ ei,
                                               int* __restrict__ cnt2, int* __restrict__ list2){
  long long gid = (long long)blockIdx.x * blockDim.x + threadIdx.x;
  long long e4 = gid * 4;
  int t = (int)(e4 >> 18);
  int e = (int)(e4 & (NE - 1));
  const int* dstp = ei + (size_t)t * 2 * NE + NE + e;
  int4 d = *(const int4*)dstp;
  int dd[4] = {d.x, d.y, d.z, d.w};
  #pragma unroll
  for (int q = 0; q < 4; q++){
    if (dd[q] == 0){
      int pos = atomicAdd(&cnt2[t], 1);
      if (pos < CAP2) list2[t * CAP2 + pos] = e + q;
    }
  }
}

// ---- K2: build active node set S = {sources of dst-0 edges} ∪ {0}, with slot map ----
// slot value is never read within this kernel (CAS losers skip) -> relaxed store, no wbl2.
__global__ __launch_bounds__(128) void k_build(const int* __restrict__ ei, const int* __restrict__ cnt2,
                                               const int* __restrict__ list2, int* __restrict__ scnt,
                                               int* __restrict__ Slist, int* __restrict__ slot_of){
  int t = blockIdx.x;
  int* so = slot_of + (size_t)t * NN;
  int m = min(cnt2[t], CAP2);
  for (int i = threadIdx.x; i < m + 1; i += blockDim.x){
    int u = (i == m) ? 0 : ei[(size_t)t * 2 * NE + list2[t * CAP2 + i]];
    int old = atomicCAS(&so[u], -1, -2);
    if (old == -1){
      int s = atomicAdd(&scnt[t], 1);
      Slist[t * SCAP + s] = u;
      __hip_atomic_store(&so[u], s, __ATOMIC_RELAXED, __HIP_MEMORY_SCOPE_AGENT);
    }
  }
}

// ---- K3: collect in-edges of every node in S ----
__global__ __launch_bounds__(256) void k_scan1(const int* __restrict__ ei, const int* __restrict__ slot_of,
                                               int* __restrict__ ecnt1, int* __restrict__ elist1){
  long long gid = (long long)blockIdx.x * blockDim.x + threadIdx.x;
  long long e4 = gid * 4;
  int t = (int)(e4 >> 18);
  int e = (int)(e4 & (NE - 1));
  const int* dstp = ei + (size_t)t * 2 * NE + NE + e;
  int4 d = *(const int4*)dstp;
  int dd[4] = {d.x, d.y, d.z, d.w};
  #pragma unroll
  for (int q = 0; q < 4; q++){
    int sl = slot_of[(size_t)t * NN + dd[q]];
    if (sl >= 0){
      int pos = atomicAdd(&ecnt1[t * SCAP + sl], 1);
      if (pos < DEGCAP) elist1[((size_t)t * SCAP + sl) * DEGCAP + pos] = e + q;
    }
  }
}

// ---- K4: layer-1 GAT at active nodes. One wave per (t, slot). ----
__global__ __launch_bounds__(64) void k_gat1(const float* __restrict__ x, const int* __restrict__ ei,
                                             const float* __restrict__ Wl1, const float* __restrict__ attl,
                                             const float* __restrict__ attr, const float* __restrict__ b1,
                                             const int* __restrict__ scnt, const int* __restrict__ Slist,
                                             const int* __restrict__ ecnt1, const int* __restrict__ elist1,
                                             float* __restrict__ h1){
  int t = blockIdx.y, s = blockIdx.x;
  if (s >= scnt[t]) return;
  int lane = threadIdx.x;
  int u = Slist[t * SCAP + s];
  int deg = min(ecnt1[t * SCAP + s], DEGCAP);
  int tot = deg + 1;                      // + self loop (appended after edges; id >= NE, never special)
  bool two = tot > 64;                    // wave-uniform: second chunk needed (rare: deg ~ Poisson(16))
  const float* xt = x + (size_t)t * NN * FIN;
  const int* srcp = ei + (size_t)t * 2 * NE;
  const int* el = elist1 + ((size_t)t * SCAP + s) * DEGCAP;

  float xu[FIN];
  #pragma unroll
  for (int f = 0; f < FIN; f++) xu[f] = xt[(size_t)u * FIN + f];

  // chunk 0 (lanes 0..63)
  bool act0 = lane < tot;
  int eid0 = 1 << 29;
  int su0 = u;
  if (lane < deg){ int e = el[lane]; eid0 = e; su0 = srcp[e]; }
  float xsrc0[FIN];
  #pragma unroll
  for (int f = 0; f < FIN; f++) xsrc0[f] = xt[(size_t)su0 * FIN + f];

  // chunk 1 (lanes 64..127) — only if deg+1 > 64
  bool act1 = false; int eid1 = 1 << 29;
  float xsrc1[FIN];
  if (two){
    int idx = 64 + lane;
    act1 = idx < tot;
    int su1 = u;
    if (idx < deg){ int e = el[idx]; eid1 = e; su1 = srcp[e]; }
    #pragma unroll
    for (int f = 0; f < FIN; f++) xsrc1[f] = xt[(size_t)su1 * FIN + f];
  }

  float* h1p = h1 + ((size_t)t * SCAP + s) * HID;
  for (int h = 0; h < H1H; h++){
    // xl of dst node -> ar
    float xlu[C1C];
    #pragma unroll
    for (int c = 0; c < C1C; c++){
      float v = 0.f;
      #pragma unroll
      for (int f = 0; f < FIN; f++) v += xu[f] * Wl1[f * HID + h * C1C + c];
      xlu[c] = v;
    }
    float ar = 0.f;
    #pragma unroll
    for (int c = 0; c < C1C; c++) ar += xlu[c] * attr[h * C1C + c];

    float xls0[C1C], xls1[C1C];
    float raw0, raw1 = -INFINITY;
    {
      float al = 0.f;
      #pragma unroll
      for (int c = 0; c < C1C; c++){
        float v = 0.f;
        #pragma unroll
        for (int f = 0; f < FIN; f++) v += xsrc0[f] * Wl1[f * HID + h * C1C + c];
        xls0[c] = v;
        al += v * attl[h * C1C + c];
      }
      raw0 = act0 ? leaky(al + ar) : -INFINITY;
    }
    if (two){
      float al = 0.f;
      #pragma unroll
      for (int c = 0; c < C1C; c++){
        float v = 0.f;
        #pragma unroll
        for (int f = 0; f < FIN; f++) v += xsrc1[f] * Wl1[f * HID + h * C1C + c];
        xls1[c] = v;
        al += v * attl[h * C1C + c];
      }
      raw1 = act1 ? leaky(al + ar) : -INFINITY;
    }
    float M = wave_max(fmaxf(raw0, raw1));
    float ex0 = act0 ? expf(raw0 - M) : 0.f;
    float ex1 = act1 ? expf(raw1 - M) : 0.f;
    float S = wave_sum(ex0 + ex1);
    float den = S + 1e-16f;
    float alpha0 = apply_edit(ex0 / den, eid0);
    float alpha1 = two ? apply_edit(ex1 / den, eid1) : 0.f;

    #pragma unroll
    for (int c = 0; c < C1C; c++){
      float contrib = xls0[c] * alpha0;
      if (two) contrib += xls1[c] * alpha1;
      contrib = wave_sum(contrib);
      if (lane == 0){
        float v = contrib + b1[h * C1C + c];
        h1p[h * C1C + c] = v > 0.f ? v : expm1f(v);   // ELU
      }
    }
  }
}

// ---- K5: layer-2 GAT at node 0 only -> series[t]. One wave per t. ----
__global__ __launch_bounds__(64) void k_gat2(const int* __restrict__ ei, const float* __restrict__ Wl2,
                                             const float* __restrict__ attl2_, const float* __restrict__ attr2_,
                                             const float* __restrict__ b2, const int* __restrict__ cnt2,
                                             const int* __restrict__ list2, const int* __restrict__ slot_of,
                                             const float* __restrict__ h1, float* __restrict__ series){
  int t = blockIdx.x; int lane = threadIdx.x;
  int deg = min(cnt2[t], CAP2);
  int tot = deg + 1;
  const int* srcp = ei + (size_t)t * 2 * NE;
  const int* so = slot_of + (size_t)t * NN;
  float attl2 = attl2_[0], attr2 = attr2_[0];
  int sl0 = so[0];
  const float* h1t = h1 + (size_t)t * SCAP * HID;

  float x0 = 0.f;
  for (int k = 0; k < HID; k++) x0 += h1t[(size_t)sl0 * HID + k] * Wl2[k];

  bool act[2]; int eid[2]; float xl2[2];
  #pragma unroll
  for (int ch = 0; ch < 2; ch++){
    int idx = ch * 64 + lane;
    act[ch] = idx < tot;
    eid[ch] = 1 << 29;
    int sl = sl0;
    if (idx < deg){ int e = list2[t * CAP2 + idx]; eid[ch] = e; sl = so[srcp[e]]; }
    float v = 0.f;
    if (act[ch]) for (int k = 0; k < HID; k++) v += h1t[(size_t)sl * HID + k] * Wl2[k];
    xl2[ch] = v;
  }
  float raw[2];
  #pragma unroll
  for (int ch = 0; ch < 2; ch++) raw[ch] = act[ch] ? leaky(attl2 * xl2[ch] + attr2 * x0) : -INFINITY;
  float M = wave_max(fmaxf(raw[0], raw[1]));
  float ex[2];
  #pragma unroll
  for (int ch = 0; ch < 2; ch++) ex[ch] = act[ch] ? expf(raw[ch] - M) : 0.f;
  float S = wave_sum(ex[0] + ex[1]);
  float den = S + 1e-16f;
  float contrib = apply_edit(ex[0] / den, eid[0]) * xl2[0] + apply_edit(ex[1] / den, eid[1]) * xl2[1];
  contrib = wave_sum(contrib);
  if (lane == 0) series[t] = contrib + b2[0];   // 1 head, mean == identity
}

// ---- K7: LSTM, 3-station pipeline. blocks 0-31: layer0 (Whh0), 32-63: Wih1, 64-95: layer1 (Whh1). ----
// Round 1-3 post-mortems:
//  * VGPR=100/116 regardless of launch_bounds/pin: the w4[32] ARRAY was lowered to scratch before
//    any pin could act -> now 32 NAMED float4 locals via macros (nothing to lower) + volatile pin
//    (non-rematerializable) under the 256-VGPR cap of __launch_bounds__(512,2).
//  * __threadfence (buffer_wbl2) + release flag (wbl2) + acquire poll (buffer_inv per iteration)
//    caused L2 writeback/invalidate storms every step: ~3us/step fence cost AND evicted the weight
//    lines, forcing a ~256KB/step L2 re-stream. Fix: RELAXED agent atomics everywhere (sc0 sc1 on
//    the access -> device-coherent, no cache maintenance); ordering via the existing __syncthreads
//    (compiler drains vmcnt(0) before s_barrier, so all waves' data stores complete before lane 0
//    issues the flag store). Consumer: relaxed poll (batched: read the value, bank ready steps),
//    barrier, relaxed data loads.
#define AT_LOADR(p)    __hip_atomic_load((p), __ATOMIC_RELAXED, __HIP_MEMORY_SCOPE_AGENT)
#define AT_STORER(p,v) __hip_atomic_store((p), (v), __ATOMIC_RELAXED, __HIP_MEMORY_SCOPE_AGENT)

#define REP32(M) M(0)M(1)M(2)M(3)M(4)M(5)M(6)M(7)M(8)M(9)M(10)M(11)M(12)M(13)M(14)M(15)\
                 M(16)M(17)M(18)M(19)M(20)M(21)M(22)M(23)M(24)M(25)M(26)M(27)M(28)M(29)M(30)M(31)
#define WDECL(i) float4 w##i;
#define WLOAD(i) w##i = Wr[i];
#define WPIN(i)  asm volatile("" : "+v"(w##i.x), "+v"(w##i.y), "+v"(w##i.z), "+v"(w##i.w));
#define WFMA(i)  { float4 hv = h4[i]; a0 = fmaf(w##i.x, hv.x, a0); a1 = fmaf(w##i.y, hv.y, a1); \
                   a2 = fmaf(w##i.z, hv.z, a2); a3 = fmaf(w##i.w, hv.w, a3); }

__global__ __launch_bounds__(512, 2) void k_lstm(const float* __restrict__ series,
    const float* __restrict__ Wih0, const float* __restrict__ Whh0,
    const float* __restrict__ bih0, const float* __restrict__ bhh0,
    const float* __restrict__ Wih1, const float* __restrict__ Whh1,
    const float* __restrict__ bih1, const float* __restrict__ bhh1,
    const float* __restrict__ Wlin, const float* __restrict__ blin,
    float* __restrict__ h0g, float* __restrict__ xpart,
    int* __restrict__ flagA, int* __restrict__ flagB, float* __restrict__ out){
  int j = threadIdx.x;
  int st = blockIdx.x >> 5;
  int b = blockIdx.x & 31;     // stations of batch b land on blocks b, b+32, b+64 -> same XCD (32%8==0)
  __shared__ __align__(16) float h_lds[LH];
  __shared__ __align__(16) float c_lds[LH];
  __shared__ float gate_lds[G4];
  __shared__ float s_series[NL];
  __shared__ int rdy_lds;
  const float4* h4 = (const float4*)h_lds;

  if (st == 0){
    const float4* Wr = (const float4*)(Whh0 + (size_t)j * LH);
    REP32(WDECL)
    REP32(WLOAD)
    REP32(WPIN)
    float wih = Wih0[j];
    float bsum = bih0[j] + bhh0[j];
    if (j < LH){ h_lds[j] = 0.f; c_lds[j] = 0.f; }
    if (j < NL) s_series[j] = series[b + j];
    __syncthreads();
    for (int t = 0; t < NL; t++){
      float a0 = 0.f, a1 = 0.f, a2 = 0.f, a3 = 0.f;
      REP32(WFMA)
      float acc = fmaf(wih, s_series[t], bsum) + (a0 + a1) + (a2 + a3);
      gate_lds[j] = acc;
      __syncthreads();
      if (j < LH){
        float ig = sigmoidf(gate_lds[j]);
        float fg = sigmoidf(gate_lds[LH + j]);
        float gg = tanhf(gate_lds[2 * LH + j]);
        float og = sigmoidf(gate_lds[3 * LH + j]);
        float c = fg * c_lds[j] + ig * gg;
        float h = og * tanhf(c);
        c_lds[j] = c; h_lds[j] = h;
        AT_STORER(&h0g[(b * NL + t) * LH + j], h);
      }
      __syncthreads();   // drains all waves' h0g stores (vmcnt(0) before s_barrier)
      if (j == 0) AT_STORER(&flagA[b], t + 1);
    }
  } else if (st == 1){
    const float4* Wr = (const float4*)(Wih1 + (size_t)j * LH);
    REP32(WDECL)
    REP32(WLOAD)
    REP32(WPIN)
    int ready = 0;
    for (int t = 0; t < NL; t++){
      if (ready <= t){
        if (j == 0){
          int f;
          while ((f = AT_LOADR(&flagA[b])) < t + 1) __builtin_amdgcn_s_sleep(1);
          rdy_lds = f;
        }
        __syncthreads();
        ready = rdy_lds;
      }
      if (j < LH) h_lds[j] = AT_LOADR(&h0g[(b * NL + t) * LH + j]);
      __syncthreads();
      float a0 = 0.f, a1 = 0.f, a2 = 0.f, a3 = 0.f;
      REP32(WFMA)
      AT_STORER(&xpart[(b * NL + t) * G4 + j], (a0 + a1) + (a2 + a3));
      __syncthreads();   // LDS h reads done for t + xpart stores drained
      if (j == 0) AT_STORER(&flagB[b], t + 1);
    }
  } else {
    const float4* Wr = (const float4*)(Whh1 + (size_t)j * LH);
    REP32(WDECL)
    REP32(WLOAD)
    REP32(WPIN)
    float bsum = bih1[j] + bhh1[j];
    if (j < LH){ h_lds[j] = 0.f; c_lds[j] = 0.f; }
    __syncthreads();
    int ready = 0;
    for (int t = 0; t < NL; t++){
      if (ready <= t){
        if (j == 0){
          int f;
          while ((f = AT_LOADR(&flagB[b])) < t + 1) __builtin_amdgcn_s_sleep(1);
          rdy_lds = f;
        }
        __syncthreads();
        ready = rdy_lds;
      }
      float xj = AT_LOADR(&xpart[(b * NL + t) * G4 + j]);
      float a0 = 0.f, a1 = 0.f, a2 = 0.f, a3 = 0.f;
      REP32(WFMA)
      float acc = xj + bsum + (a0 + a1) + (a2 + a3);
      gate_lds[j] = acc;
      __syncthreads();
      if (j < LH){
        float ig = sigmoidf(gate_lds[j]);
        float fg = sigmoidf(gate_lds[LH + j]);
        float gg = tanhf(gate_lds[2 * LH + j]);
        float og = sigmoidf(gate_lds[3 * LH + j]);
        float c = fg * c_lds[j] + ig * gg;
        float h = og * tanhf(c);
        c_lds[j] = c; h_lds[j] = h;
      }
      __syncthreads();
    }
    if (j == 0){
      float s2 = blin[0];
      for (int k = 0; k < LH; k++) s2 += Wlin[k] * h_lds[k];
      out[b] = s2;
    }
  }
}

extern "C" void kernel_launch(void* const* d_in, const int* in_sizes, int n_in,
                              void* d_out, int out_size, void* d_ws, size_t ws_size,
                              hipStream_t stream) {
  const float* x     = (const float*)d_in[0];
  const int*   ei    = (const int*)  d_in[1];
  const float* Wl1   = (const float*)d_in[2];
  const float* attl1 = (const float*)d_in[3];
  const float* attr1 = (const float*)d_in[4];
  const float* b1    = (const float*)d_in[5];
  const float* Wl2   = (const float*)d_in[6];
  const float* attl2 = (const float*)d_in[7];
  const float* attr2 = (const float*)d_in[8];
  const float* b2    = (const float*)d_in[9];
  const float* Wih0  = (const float*)d_in[10];
  const float* Whh0  = (const float*)d_in[11];
  const float* bih0  = (const float*)d_in[12];
  const float* bhh0  = (const float*)d_in[13];
  const float* Wih1  = (const float*)d_in[14];
  const float* Whh1  = (const float*)d_in[15];
  const float* bih1  = (const float*)d_in[16];
  const float* bhh1  = (const float*)d_in[17];
  const float* Wlin  = (const float*)d_in[18];
  const float* blin  = (const float*)d_in[19];
  float* out = (float*)d_out;

  char* wsb = (char*)d_ws;
  size_t off = 0;
  auto alloc = [&](size_t bytes)->void*{
    void* p = wsb + off;
    off += (bytes + 255) & ~(size_t)255;
    return p;
  };
  // control region (must be zeroed each launch — ws is poisoned 0xAA)
  int* cnt2  = (int*)alloc(T * 4);
  int* scnt  = (int*)alloc(T * 4);
  int* ecnt1 = (int*)alloc(T * SCAP * 4);
  int* flagA = (int*)alloc(NB * 4);
  int* flagB = (int*)alloc(NB * 4);
  size_t ctrl_bytes = off;
  int* slot_of = (int*)alloc((size_t)T * NN * 4);       // memset 0xFF -> -1
  int* list2   = (int*)alloc((size_t)T * CAP2 * 4);
  int* Slist   = (int*)alloc((size_t)T * SCAP * 4);
  int* elist1  = (int*)alloc((size_t)T * SCAP * DEGCAP * 4);
  float* h1    = (float*)alloc((size_t)T * SCAP * HID * 4);
  float* series= (float*)alloc(T * 4);
  float* h0g   = (float*)alloc((size_t)NB * NL * LH * 4);
  float* xpart = (float*)alloc((size_t)NB * NL * G4 * 4);

  hipMemsetAsync(d_ws, 0, ctrl_bytes, stream);
  hipMemsetAsync(slot_of, 0xFF, (size_t)T * NN * 4, stream);

  k_scan0<<<T * NE / 4 / 256, 256, 0, stream>>>(ei, cnt2, list2);
  k_build<<<T, 128, 0, stream>>>(ei, cnt2, list2, scnt, Slist, slot_of);
  k_scan1<<<T * NE / 4 / 256, 256, 0, stream>>>(ei, slot_of, ecnt1, elist1);
  k_gat1<<<dim3(SCAP, T), 64, 0, stream>>>(x, ei, Wl1, attl1, attr1, b1, scnt, Slist, ecnt1, elist1, h1);
  k_gat2<<<T, 64, 0, stream>>>(ei, Wl2, attl2, attr2, b2, cnt2, list2, slot_of, h1, series);
  k_lstm<<<96, 512, 0, stream>>>(series, Wih0, Whh0, bih0, bhh0, Wih1, Whh1, bih1, bhh1,
                                 Wlin, blin, h0g, xpart, flagA, flagB, out);
}

// Round 5
// 415.746 us; speedup vs baseline: 1.3479x; 1.1505x over previous
//
#include <hip/hip_runtime.h>
#include <math.h>

#define T 64
#define NN 16384
#define NE 262144
#define FIN 8
#define H1H 12
#define C1C 16
#define HID 192
#define CAP2 95      // max recorded in-edges of node 0 per t (Poisson(16); P(>=95) ~ 0)
#define SCAP 96      // max active nodes per t (CAP2 sources + node 0)
#define DEGCAP 127   // max recorded in-degree of an active node (Poisson(16))
#define LH 128
#define G4 512
#define NB 32
#define NL 32

#define DEV __device__ __forceinline__

DEV float wave_max(float v){
  #pragma unroll
  for (int m = 32; m; m >>= 1) v = fmaxf(v, __shfl_xor(v, m));
  return v;
}
DEV float wave_sum(float v){
  #pragma unroll
  for (int m = 32; m; m >>= 1) v += __shfl_xor(v, m);
  return v;
}
DEV float leaky(float x){ return x >= 0.f ? x : 0.2f * x; }
DEV float sigmoidf(float x){ return 1.f / (1.f + expf(-x)); }

// alpha = 0.8*a + 0.1*s + 0.1*v with s: rows {1,2,12,19,22}->0, {7,14}->1
//                                  v: rows {10,13}->0.5, {17}->0
// => rows {1,2,7,10,12,13,14,17,19,22}: 0.9a; {7,14}: +0.1; {10,13}: +0.05
DEV float apply_edit(float a, int eid){
  if (eid >= 32) return a;
  const unsigned m09 = (1u<<1)|(1u<<2)|(1u<<7)|(1u<<10)|(1u<<12)|(1u<<13)|(1u<<14)|(1u<<17)|(1u<<19)|(1u<<22);
  const unsigned mp1 = (1u<<7)|(1u<<14);
  const unsigned mp05 = (1u<<10)|(1u<<13);
  unsigned b = 1u << eid;
  float r = (m09 & b) ? 0.9f * a : a;
  if (mp1 & b) r += 0.1f;
  if (mp05 & b) r += 0.05f;
  return r;
}

// ---- K1: find edges with dst==0 per timestep ----
__global__ __launch_bounds__(256) void k_scan0(const int* __restrict__ ei,
                                               int* __restrict__ cnt2, int* __restrict__ list2){
  long long gid = (long long)blockIdx.x * blockDim.x + threadIdx.x;
  long long e4 = gid * 4;
  int t = (int)(e4 >> 18);
  int e = (int)(e4 & (NE - 1));
  const int* dstp = ei + (size_t)t * 2 * NE + NE + e;
  int4 d = *(const int4*)dstp;
  int dd[4] = {d.x, d.y, d.z, d.w};
  #pragma unroll
  for (int q = 0; q < 4; q++){
    if (dd[q] == 0){
      int pos = atomicAdd(&cnt2[t], 1);
      if (pos < CAP2) list2[t * CAP2 + pos] = e + q;
    }
  }
}

// ---- K2: build active node set S = {sources of dst-0 edges} ∪ {0}, with slot map ----
// slot value is never read within this kernel (CAS losers skip) -> relaxed store, no wbl2.
__global__ __launch_bounds__(128) void k_build(const int* __restrict__ ei, const int* __restrict__ cnt2,
                                               const int* __restrict__ list2, int* __restrict__ scnt,
                                               int* __restrict__ Slist, int* __restrict__ slot_of){
  int t = blockIdx.x;
  int* so = slot_of + (size_t)t * NN;
  int m = min(cnt2[t], CAP2);
  for (int i = threadIdx.x; i < m + 1; i += blockDim.x){
    int u = (i == m) ? 0 : ei[(size_t)t * 2 * NE + list2[t * CAP2 + i]];
    int old = atomicCAS(&so[u], -1, -2);
    if (old == -1){
      int s = atomicAdd(&scnt[t], 1);
      Slist[t * SCAP + s] = u;
      __hip_atomic_store(&so[u], s, __ATOMIC_RELAXED, __HIP_MEMORY_SCOPE_AGENT);
    }
  }
}

// ---- K3: collect in-edges of every node in S ----
__global__ __launch_bounds__(256) void k_scan1(const int* __restrict__ ei, const int* __restrict__ slot_of,
                                               int* __restrict__ ecnt1, int* __restrict__ elist1){
  long long gid = (long long)blockIdx.x * blockDim.x + threadIdx.x;
  long long e4 = gid * 4;
  int t = (int)(e4 >> 18);
  int e = (int)(e4 & (NE - 1));
  const int* dstp = ei + (size_t)t * 2 * NE + NE + e;
  int4 d = *(const int4*)dstp;
  int dd[4] = {d.x, d.y, d.z, d.w};
  #pragma unroll
  for (int q = 0; q < 4; q++){
    int sl = slot_of[(size_t)t * NN + dd[q]];
    if (sl >= 0){
      int pos = atomicAdd(&ecnt1[t * SCAP + sl], 1);
      if (pos < DEGCAP) elist1[((size_t)t * SCAP + sl) * DEGCAP + pos] = e + q;
    }
  }
}

// ---- K4: layer-1 GAT at active nodes. One wave per (t, slot, head). ----
// Round-4 post-mortem: one wave per (t,slot) doing all 12 heads serially = ~1100 waves on 1024
// SIMDs -> 1 wave/SIMD, pure latency-bound on swizzle-reduction chains (VALUBusy 12%). Head dim
// is parallel after the gather: grid z = head -> 12x waves, 12x less per-wave latency.
// __launch_bounds__(64,4): 128-VGPR cap so xls arrays + 16 reduction chains stay in regs (r4's
// 64-VGPR alloc serialized them), 4 waves/SIMD co-residency for latency hiding.
__global__ __launch_bounds__(64, 4) void k_gat1(const float* __restrict__ x, const int* __restrict__ ei,
                                             const float* __restrict__ Wl1, const float* __restrict__ attl,
                                             const float* __restrict__ attr, const float* __restrict__ b1,
                                             const int* __restrict__ scnt, const int* __restrict__ Slist,
                                             const int* __restrict__ ecnt1, const int* __restrict__ elist1,
                                             float* __restrict__ h1){
  int t = blockIdx.y, s = blockIdx.x, h = blockIdx.z;
  if (s >= scnt[t]) return;
  int lane = threadIdx.x;
  int u = Slist[t * SCAP + s];
  int deg = min(ecnt1[t * SCAP + s], DEGCAP);
  int tot = deg + 1;                      // + self loop (appended after edges; id >= NE, never special)
  bool two = tot > 64;                    // wave-uniform: second chunk needed (rare: deg ~ Poisson(16))
  const float* xt = x + (size_t)t * NN * FIN;
  const int* srcp = ei + (size_t)t * 2 * NE;
  const int* el = elist1 + ((size_t)t * SCAP + s) * DEGCAP;

  float4 xu_a = ((const float4*)(xt + (size_t)u * FIN))[0];
  float4 xu_b = ((const float4*)(xt + (size_t)u * FIN))[1];
  float xu[FIN] = {xu_a.x, xu_a.y, xu_a.z, xu_a.w, xu_b.x, xu_b.y, xu_b.z, xu_b.w};

  // chunk 0 (lanes 0..63)
  bool act0 = lane < tot;
  int eid0 = 1 << 29;
  int su0 = u;
  if (lane < deg){ int e = el[lane]; eid0 = e; su0 = srcp[e]; }
  float4 xs0a = ((const float4*)(xt + (size_t)su0 * FIN))[0];
  float4 xs0b = ((const float4*)(xt + (size_t)su0 * FIN))[1];
  float xsrc0[FIN] = {xs0a.x, xs0a.y, xs0a.z, xs0a.w, xs0b.x, xs0b.y, xs0b.z, xs0b.w};

  // chunk 1 (lanes 64..127) — only if deg+1 > 64
  bool act1 = false; int eid1 = 1 << 29;
  float xsrc1[FIN];
  if (two){
    int idx = 64 + lane;
    act1 = idx < tot;
    int su1 = u;
    if (idx < deg){ int e = el[idx]; eid1 = e; su1 = srcp[e]; }
    float4 xs1a = ((const float4*)(xt + (size_t)su1 * FIN))[0];
    float4 xs1b = ((const float4*)(xt + (size_t)su1 * FIN))[1];
    #pragma unroll
    for (int f = 0; f < 4; f++) xsrc1[f] = (&xs1a.x)[f];
    #pragma unroll
    for (int f = 0; f < 4; f++) xsrc1[4 + f] = (&xs1b.x)[f];
  }

  const float* Wh = Wl1 + h * C1C;        // column block of head h: Wh[f*HID + c]
  const float* attlh = attl + h * C1C;
  const float* attrh = attr + h * C1C;

  // ar (same for all lanes): dst-node projection dotted with att_r — no xlu array kept
  float ar = 0.f;
  #pragma unroll
  for (int c = 0; c < C1C; c++){
    float v = 0.f;
    #pragma unroll
    for (int f = 0; f < FIN; f++) v = fmaf(xu[f], Wh[f * HID + c], v);
    ar = fmaf(v, attrh[c], ar);
  }

  float xls0[C1C];
  float al0 = 0.f;
  #pragma unroll
  for (int c = 0; c < C1C; c++){
    float v = 0.f;
    #pragma unroll
    for (int f = 0; f < FIN; f++) v = fmaf(xsrc0[f], Wh[f * HID + c], v);
    xls0[c] = v;
    al0 = fmaf(v, attlh[c], al0);
  }
  float raw0 = act0 ? leaky(al0 + ar) : -INFINITY;

  float xls1[C1C];
  float raw1 = -INFINITY;
  if (two){
    float al1 = 0.f;
    #pragma unroll
    for (int c = 0; c < C1C; c++){
      float v = 0.f;
      #pragma unroll
      for (int f = 0; f < FIN; f++) v = fmaf(xsrc1[f], Wh[f * HID + c], v);
      xls1[c] = v;
      al1 = fmaf(v, attlh[c], al1);
    }
    raw1 = act1 ? leaky(al1 + ar) : -INFINITY;
  }

  float M = wave_max(fmaxf(raw0, raw1));
  float ex0 = act0 ? expf(raw0 - M) : 0.f;
  float ex1 = act1 ? expf(raw1 - M) : 0.f;
  float S = wave_sum(ex0 + ex1);
  float den = S + 1e-16f;
  float alpha0 = apply_edit(ex0 / den, eid0);
  float alpha1 = two ? apply_edit(ex1 / den, eid1) : 0.f;

  // 16 independent reductions, batched level-by-level so the chains pipeline
  float sum[C1C];
  #pragma unroll
  for (int c = 0; c < C1C; c++){
    sum[c] = xls0[c] * alpha0;
    if (two) sum[c] = fmaf(xls1[c], alpha1, sum[c]);
  }
  #pragma unroll
  for (int m = 32; m; m >>= 1){
    #pragma unroll
    for (int c = 0; c < C1C; c++) sum[c] += __shfl_xor(sum[c], m);
  }
  if (lane == 0){
    float* h1p = h1 + ((size_t)t * SCAP + s) * HID + h * C1C;
    #pragma unroll
    for (int c = 0; c < C1C; c++){
      float v = sum[c] + b1[h * C1C + c];
      h1p[c] = v > 0.f ? v : expm1f(v);   // ELU
    }
  }
}

// ---- K5: layer-2 GAT at node 0 only -> series[t]. One wave per t. ----
__global__ __launch_bounds__(64) void k_gat2(const int* __restrict__ ei, const float* __restrict__ Wl2,
                                             const float* __restrict__ attl2_, const float* __restrict__ attr2_,
                                             const float* __restrict__ b2, const int* __restrict__ cnt2,
                                             const int* __restrict__ list2, const int* __restrict__ slot_of,
                                             const float* __restrict__ h1, float* __restrict__ series){
  int t = blockIdx.x; int lane = threadIdx.x;
  int deg = min(cnt2[t], CAP2);
  int tot = deg + 1;
  const int* srcp = ei + (size_t)t * 2 * NE;
  const int* so = slot_of + (size_t)t * NN;
  float attl2 = attl2_[0], attr2 = attr2_[0];
  int sl0 = so[0];
  const float* h1t = h1 + (size_t)t * SCAP * HID;

  float x0 = 0.f;
  for (int k = 0; k < HID; k++) x0 += h1t[(size_t)sl0 * HID + k] * Wl2[k];

  bool act[2]; int eid[2]; float xl2[2];
  #pragma unroll
  for (int ch = 0; ch < 2; ch++){
    int idx = ch * 64 + lane;
    act[ch] = idx < tot;
    eid[ch] = 1 << 29;
    int sl = sl0;
    if (idx < deg){ int e = list2[t * CAP2 + idx]; eid[ch] = e; sl = so[srcp[e]]; }
    float v = 0.f;
    if (act[ch]) for (int k = 0; k < HID; k++) v += h1t[(size_t)sl * HID + k] * Wl2[k];
    xl2[ch] = v;
  }
  float raw[2];
  #pragma unroll
  for (int ch = 0; ch < 2; ch++) raw[ch] = act[ch] ? leaky(attl2 * xl2[ch] + attr2 * x0) : -INFINITY;
  float M = wave_max(fmaxf(raw[0], raw[1]));
  float ex[2];
  #pragma unroll
  for (int ch = 0; ch < 2; ch++) ex[ch] = act[ch] ? expf(raw[ch] - M) : 0.f;
  float S = wave_sum(ex[0] + ex[1]);
  float den = S + 1e-16f;
  float contrib = apply_edit(ex[0] / den, eid[0]) * xl2[0] + apply_edit(ex[1] / den, eid[1]) * xl2[1];
  contrib = wave_sum(contrib);
  if (lane == 0) series[t] = contrib + b2[0];   // 1 head, mean == identity
}

// ---- K7: LSTM, 3-station pipeline. blocks 0-31: layer0 (Whh0), 32-63: Wih1, 64-95: layer1 (Whh1). ----
// Round 1-3 post-mortems:
//  * VGPR=100/116 regardless of launch_bounds/pin: the w4[32] ARRAY was lowered to scratch before
//    any pin could act -> 32 NAMED float4 locals via macros (nothing to lower) + volatile pin.
//  * __threadfence + release/acquire atomics caused L2 wbl2/inv storms every step (~5us/step).
//    Fix (r4, confirmed: k_lstm left top-5): RELAXED agent atomics, ordering via __syncthreads.
#define AT_LOADR(p)    __hip_atomic_load((p), __ATOMIC_RELAXED, __HIP_MEMORY_SCOPE_AGENT)
#define AT_STORER(p,v) __hip_atomic_store((p), (v), __ATOMIC_RELAXED, __HIP_MEMORY_SCOPE_AGENT)

#define REP32(M) M(0)M(1)M(2)M(3)M(4)M(5)M(6)M(7)M(8)M(9)M(10)M(11)M(12)M(13)M(14)M(15)\
                 M(16)M(17)M(18)M(19)M(20)M(21)M(22)M(23)M(24)M(25)M(26)M(27)M(28)M(29)M(30)M(31)
#define WDECL(i) float4 w##i;
#define WLOAD(i) w##i = Wr[i];
#define WPIN(i)  asm volatile("" : "+v"(w##i.x), "+v"(w##i.y), "+v"(w##i.z), "+v"(w##i.w));
#define WFMA(i)  { float4 hv = h4[i]; a0 = fmaf(w##i.x, hv.x, a0); a1 = fmaf(w##i.y, hv.y, a1); \
                   a2 = fmaf(w##i.z, hv.z, a2); a3 = fmaf(w##i.w, hv.w, a3); }

__global__ __launch_bounds__(512, 2) void k_lstm(const float* __restrict__ series,
    const float* __restrict__ Wih0, const float* __restrict__ Whh0,
    const float* __restrict__ bih0, const float* __restrict__ bhh0,
    const float* __restrict__ Wih1, const float* __restrict__ Whh1,
    const float* __restrict__ bih1, const float* __restrict__ bhh1,
    const float* __restrict__ Wlin, const float* __restrict__ blin,
    float* __restrict__ h0g, float* __restrict__ xpart,
    int* __restrict__ flagA, int* __restrict__ flagB, float* __restrict__ out){
  int j = threadIdx.x;
  int st = blockIdx.x >> 5;
  int b = blockIdx.x & 31;     // stations of batch b land on blocks b, b+32, b+64 -> same XCD (32%8==0)
  __shared__ __align__(16) float h_lds[LH];
  __shared__ __align__(16) float c_lds[LH];
  __shared__ float gate_lds[G4];
  __shared__ float s_series[NL];
  __shared__ int rdy_lds;
  const float4* h4 = (const float4*)h_lds;

  if (st == 0){
    const float4* Wr = (const float4*)(Whh0 + (size_t)j * LH);
    REP32(WDECL)
    REP32(WLOAD)
    REP32(WPIN)
    float wih = Wih0[j];
    float bsum = bih0[j] + bhh0[j];
    if (j < LH){ h_lds[j] = 0.f; c_lds[j] = 0.f; }
    if (j < NL) s_series[j] = series[b + j];
    __syncthreads();
    for (int t = 0; t < NL; t++){
      float a0 = 0.f, a1 = 0.f, a2 = 0.f, a3 = 0.f;
      REP32(WFMA)
      float acc = fmaf(wih, s_series[t], bsum) + (a0 + a1) + (a2 + a3);
      gate_lds[j] = acc;
      __syncthreads();
      if (j < LH){
        float ig = sigmoidf(gate_lds[j]);
        float fg = sigmoidf(gate_lds[LH + j]);
        float gg = tanhf(gate_lds[2 * LH + j]);
        float og = sigmoidf(gate_lds[3 * LH + j]);
        float c = fg * c_lds[j] + ig * gg;
        float h = og * tanhf(c);
        c_lds[j] = c; h_lds[j] = h;
        AT_STORER(&h0g[(b * NL + t) * LH + j], h);
      }
      __syncthreads();   // drains all waves' h0g stores (vmcnt(0) before s_barrier)
      if (j == 0) AT_STORER(&flagA[b], t + 1);
    }
  } else if (st == 1){
    const float4* Wr = (const float4*)(Wih1 + (size_t)j * LH);
    REP32(WDECL)
    REP32(WLOAD)
    REP32(WPIN)
    int ready = 0;
    for (int t = 0; t < NL; t++){
      if (ready <= t){
        if (j == 0){
          int f;
          while ((f = AT_LOADR(&flagA[b])) < t + 1) __builtin_amdgcn_s_sleep(1);
          rdy_lds = f;
        }
        __syncthreads();
        ready = rdy_lds;
      }
      if (j < LH) h_lds[j] = AT_LOADR(&h0g[(b * NL + t) * LH + j]);
      __syncthreads();
      float a0 = 0.f, a1 = 0.f, a2 = 0.f, a3 = 0.f;
      REP32(WFMA)
      AT_STORER(&xpart[(b * NL + t) * G4 + j], (a0 + a1) + (a2 + a3));
      __syncthreads();   // LDS h reads done for t + xpart stores drained
      if (j == 0) AT_STORER(&flagB[b], t + 1);
    }
  } else {
    const float4* Wr = (const float4*)(Whh1 + (size_t)j * LH);
    REP32(WDECL)
    REP32(WLOAD)
    REP32(WPIN)
    float bsum = bih1[j] + bhh1[j];
    if (j < LH){ h_lds[j] = 0.f; c_lds[j] = 0.f; }
    __syncthreads();
    int ready = 0;
    for (int t = 0; t < NL; t++){
      if (ready <= t){
        if (j == 0){
          int f;
          while ((f = AT_LOADR(&flagB[b])) < t + 1) __builtin_amdgcn_s_sleep(1);
          rdy_lds = f;
        }
        __syncthreads();
        ready = rdy_lds;
      }
      float xj = AT_LOADR(&xpart[(b * NL + t) * G4 + j]);
      float a0 = 0.f, a1 = 0.f, a2 = 0.f, a3 = 0.f;
      REP32(WFMA)
      float acc = xj + bsum + (a0 + a1) + (a2 + a3);
      gate_lds[j] = acc;
      __syncthreads();
      if (j < LH){
        float ig = sigmoidf(gate_lds[j]);
        float fg = sigmoidf(gate_lds[LH + j]);
        float gg = tanhf(gate_lds[2 * LH + j]);
        float og = sigmoidf(gate_lds[3 * LH + j]);
        float c = fg * c_lds[j] + ig * gg;
        float h = og * tanhf(c);
        c_lds[j] = c; h_lds[j] = h;
      }
      __syncthreads();
    }
    if (j == 0){
      float s2 = blin[0];
      for (int k = 0; k < LH; k++) s2 += Wlin[k] * h_lds[k];
      out[b] = s2;
    }
  }
}

extern "C" void kernel_launch(void* const* d_in, const int* in_sizes, int n_in,
                              void* d_out, int out_size, void* d_ws, size_t ws_size,
                              hipStream_t stream) {
  const float* x     = (const float*)d_in[0];
  const int*   ei    = (const int*)  d_in[1];
  const float* Wl1   = (const float*)d_in[2];
  const float* attl1 = (const float*)d_in[3];
  const float* attr1 = (const float*)d_in[4];
  const float* b1    = (const float*)d_in[5];
  const float* Wl2   = (const float*)d_in[6];
  const float* attl2 = (const float*)d_in[7];
  const float* attr2 = (const float*)d_in[8];
  const float* b2    = (const float*)d_in[9];
  const float* Wih0  = (const float*)d_in[10];
  const float* Whh0  = (const float*)d_in[11];
  const float* bih0  = (const float*)d_in[12];
  const float* bhh0  = (const float*)d_in[13];
  const float* Wih1  = (const float*)d_in[14];
  const float* Whh1  = (const float*)d_in[15];
  const float* bih1  = (const float*)d_in[16];
  const float* bhh1  = (const float*)d_in[17];
  const float* Wlin  = (const float*)d_in[18];
  const float* blin  = (const float*)d_in[19];
  float* out = (float*)d_out;

  char* wsb = (char*)d_ws;
  size_t off = 0;
  auto alloc = [&](size_t bytes)->void*{
    void* p = wsb + off;
    off += (bytes + 255) & ~(size_t)255;
    return p;
  };
  // control region (must be zeroed each launch — ws is poisoned 0xAA)
  int* cnt2  = (int*)alloc(T * 4);
  int* scnt  = (int*)alloc(T * 4);
  int* ecnt1 = (int*)alloc(T * SCAP * 4);
  int* flagA = (int*)alloc(NB * 4);
  int* flagB = (int*)alloc(NB * 4);
  size_t ctrl_bytes = off;
  int* slot_of = (int*)alloc((size_t)T * NN * 4);       // memset 0xFF -> -1
  int* list2   = (int*)alloc((size_t)T * CAP2 * 4);
  int* Slist   = (int*)alloc((size_t)T * SCAP * 4);
  int* elist1  = (int*)alloc((size_t)T * SCAP * DEGCAP * 4);
  float* h1    = (float*)alloc((size_t)T * SCAP * HID * 4);
  float* series= (float*)alloc(T * 4);
  float* h0g   = (float*)alloc((size_t)NB * NL * LH * 4);
  float* xpart = (float*)alloc((size_t)NB * NL * G4 * 4);

  hipMemsetAsync(d_ws, 0, ctrl_bytes, stream);
  hipMemsetAsync(slot_of, 0xFF, (size_t)T * NN * 4, stream);

  k_scan0<<<T * NE / 4 / 256, 256, 0, stream>>>(ei, cnt2, list2);
  k_build<<<T, 128, 0, stream>>>(ei, cnt2, list2, scnt, Slist, slot_of);
  k_scan1<<<T * NE / 4 / 256, 256, 0, stream>>>(ei, slot_of, ecnt1, elist1);
  k_gat1<<<dim3(SCAP, T, H1H), 64, 0, stream>>>(x, ei, Wl1, attl1, attr1, b1, scnt, Slist, ecnt1, elist1, h1);
  k_gat2<<<T, 64, 0, stream>>>(ei, Wl2, attl2, attr2, b2, cnt2, list2, slot_of, h1, series);
  k_lstm<<<96, 512, 0, stream>>>(series, Wih0, Whh0, bih0, bhh0, Wih1, Whh1, bih1, bhh1,
                                 Wlin, blin, h0g, xpart, flagA, flagB, out);
}